// Round 4
// baseline (3704.186 us; speedup 1.0000x reference)
//
#include <hip/hip_runtime.h>
#include <hip/hip_bf16.h>
#include <stdint.h>

#define NB 8
#define NPTS 8192
#define NCH 64
#define NPOINT 2048
#define NSAMPLE 32
#define R2 0.04f

// ---------------------------------------------------------------------------
// FPS: one block per batch. Exact IEEE replication of
//   d = ((dx*dx + dy*dy) + dz*dz);  dist = min(dist, d);  argmax (first index)
// (elementwise+reduce path: separate mul/add, NO fma — verified bit-exact)
// ---------------------------------------------------------------------------
__global__ __launch_bounds__(1024) void fps_kernel(const float* __restrict__ xyz,
                                                   float* __restrict__ out)
{
  const int b = blockIdx.x;
  const int t = threadIdx.x;
  const float* xb = xyz + (size_t)b*3*NPTS;
  float px[8], py[8], pz[8], dist[8];
  #pragma unroll
  for (int k=0;k<8;k++){
    int i = k*1024 + t;
    px[k]=xb[i]; py[k]=xb[NPTS+i]; pz[k]=xb[2*NPTS+i];
    dist[k]=1e10f;
  }
  __shared__ float s_c[3];
  __shared__ int s_far;
  __shared__ unsigned long long s_red[16];
  if (t==0) s_far = 0;
  __syncthreads();
  float* oxb = out + (size_t)b*3*NPOINT;
  for (int s=0;s<NPOINT;s++){
    const int far = s_far;
    if (t == (far & 1023)){
      const int k = far >> 10;
      s_c[0]=px[k]; s_c[1]=py[k]; s_c[2]=pz[k];
      oxb[s]=px[k]; oxb[NPOINT+s]=py[k]; oxb[2*NPOINT+s]=pz[k];
    }
    __syncthreads();
    const float cx=s_c[0], cy=s_c[1], cz=s_c[2];
    float best = -1.0f; int bidx = 0;
    #pragma unroll
    for (int k=0;k<8;k++){
      float dx=__fsub_rn(px[k],cx), dy=__fsub_rn(py[k],cy), dz=__fsub_rn(pz[k],cz);
      float d = __fadd_rn(__fadd_rn(__fmul_rn(dx,dx),__fmul_rn(dy,dy)),__fmul_rn(dz,dz));
      float nd = d < dist[k] ? d : dist[k];
      dist[k]=nd;
      if (nd > best){ best = nd; bidx = (k<<10)+t; }   // strict > keeps first idx
    }
    // best >= 0 always -> float bits order-preserving
    unsigned long long key = ((unsigned long long)__float_as_uint(best) << 13)
                           | (unsigned long long)(8191 - bidx);
    #pragma unroll
    for (int off=1; off<64; off<<=1){
      unsigned long long ok = __shfl_xor(key, off, 64);
      if (ok > key) key = ok;
    }
    if ((t & 63)==0) s_red[t>>6]=key;
    __syncthreads();
    if (t < 64){
      unsigned long long k2 = (t<16) ? s_red[t] : 0ull;
      #pragma unroll
      for (int off=1; off<16; off<<=1){
        unsigned long long ok = __shfl_xor(k2, off, 64);
        if (ok > k2) k2 = ok;
      }
      if (t==0) s_far = 8191 - (int)(k2 & 8191ull);
    }
    __syncthreads();
  }
}

// ---------------------------------------------------------------------------
// Ball query: one wave per (b,s).
//   dot  = fma(z,z', fma(y,y', x*x'))      <- GEMM-path semantics (FMA chain)
//   csum/dsum = (x²+y²)+z² separate mul/add <- elementwise+reduce semantics
//   sqr  = ((-2*dot) + csum) + dsum ; keep iff !(sqr > 0.04f)
// ---------------------------------------------------------------------------
__global__ __launch_bounds__(256) void ball_kernel(const float* __restrict__ xyz,
                                                   const float* __restrict__ nxyz,
                                                   int* __restrict__ ball_idx)
{
  __shared__ int s_buf[4][NSAMPLE];
  const int wv = threadIdx.x >> 6, lane = threadIdx.x & 63;
  const int g = blockIdx.x*4 + wv;
  const int b = g >> 11;
  const int s = g & 2047;
  const float* ob = nxyz + (size_t)b*3*NPOINT;
  const float cx = ob[s], cy = ob[NPOINT+s], cz = ob[2*NPOINT+s];
  const float csum = __fadd_rn(__fadd_rn(__fmul_rn(cx,cx),__fmul_rn(cy,cy)),__fmul_rn(cz,cz));
  const float* xb = xyz + (size_t)b*3*NPTS;
  int cnt = 0;
  for (int c0=0; c0<NPTS; c0+=64){
    const int i = c0 + lane;
    float x=xb[i], y=xb[NPTS+i], z=xb[2*NPTS+i];
    float dot  = __fmaf_rn(cz, z, __fmaf_rn(cy, y, __fmul_rn(cx, x)));
    float dsum = __fadd_rn(__fadd_rn(__fmul_rn(x,x),__fmul_rn(y,y)),__fmul_rn(z,z));
    float sqr  = __fadd_rn(__fadd_rn(__fmul_rn(-2.0f,dot), csum), dsum);
    bool in = (sqr <= R2);
    unsigned long long m = __ballot(in);
    int rank = cnt + __popcll(m & ((1ull<<lane)-1ull));
    if (in && rank < NSAMPLE) s_buf[wv][rank] = i;
    cnt += (int)__popcll(m);
    if (cnt >= NSAMPLE) break;
  }
  const int first = s_buf[wv][0];
  if (lane < NSAMPLE){
    int v = (lane < cnt) ? s_buf[wv][lane] : first;
    ball_idx[(size_t)g*NSAMPLE + lane] = v;
  }
}

// ---------------------------------------------------------------------------
// MLP layer 1: gather (3 norm + 64 point channels) -> z1 = feat@W1^T + b1
// f32 z out, per-block BN partials.
// ---------------------------------------------------------------------------
__global__ __launch_bounds__(128) void mlp1_kernel(
    const float* __restrict__ xyz, const float* __restrict__ points,
    const float* __restrict__ nxyz, const int* __restrict__ ball_idx,
    const float* __restrict__ W1, const float* __restrict__ b1,
    float* __restrict__ z, float* __restrict__ part)
{
  __shared__ float wl[67*64];        // union: W (67*64) / stats tile (64*65)
  __shared__ float spA[128], spQ[128];
  const int t = threadIdx.x;
  const int m = blockIdx.x*128 + t;
  const int g = m >> 5;
  const int b = g >> 11;
  const int s = g & 2047;
  for (int e=t; e<67*64; e+=128){
    int o = e/67, c = e - o*67;
    wl[c*64+o] = W1[e];
  }
  const int idx = ball_idx[m];
  const float* xb = xyz + (size_t)b*3*NPTS;
  const float* ob = nxyz + (size_t)b*3*NPOINT;
  float f[67];
  f[0] = __fsub_rn(xb[idx],        ob[s]);
  f[1] = __fsub_rn(xb[NPTS+idx],   ob[NPOINT+s]);
  f[2] = __fsub_rn(xb[2*NPTS+idx], ob[2*NPOINT+s]);
  const float* pb = points + (size_t)b*NCH*NPTS;
  #pragma unroll
  for (int c=0;c<64;c++) f[3+c] = pb[(size_t)c*NPTS + idx];
  __syncthreads();
  float acc[64];
  #pragma unroll
  for (int o=0;o<64;o++) acc[o]=0.0f;
  #pragma unroll
  for (int c=0;c<67;c++){
    const float fc = f[c];
    const float* wr = &wl[c*64];
    #pragma unroll
    for (int q=0;q<16;q++){
      float4 w = *(const float4*)(wr + q*4);
      acc[q*4+0] = __fmaf_rn(fc, w.x, acc[q*4+0]);
      acc[q*4+1] = __fmaf_rn(fc, w.y, acc[q*4+1]);
      acc[q*4+2] = __fmaf_rn(fc, w.z, acc[q*4+2]);
      acc[q*4+3] = __fmaf_rn(fc, w.w, acc[q*4+3]);
    }
  }
  #pragma unroll
  for (int o=0;o<64;o++) acc[o] = __fadd_rn(acc[o], b1[o]);
  float* zr = z + (size_t)m*64;
  #pragma unroll
  for (int q=0;q<16;q++){
    float4 v; v.x=acc[q*4]; v.y=acc[q*4+1]; v.z=acc[q*4+2]; v.w=acc[q*4+3];
    *(float4*)(zr + q*4) = v;
  }
  // BN partial sums (two half-passes reusing wl)
  float sA=0.f, sQ=0.f;
  const int oc = t & 63;
  for (int p=0;p<2;p++){
    __syncthreads();
    if ((t>>6)==p){
      const int r = t & 63;
      #pragma unroll
      for (int j=0;j<64;j++) wl[r*65+j] = acc[j];
    }
    __syncthreads();
    const int r0 = (t>>6)*32;
    for (int r=r0; r<r0+32; r++){
      float v = wl[r*65+oc];
      sA += v; sQ = __fmaf_rn(v,v,sQ);
    }
  }
  spA[t]=sA; spQ[t]=sQ;
  __syncthreads();
  if (t<64){
    part[(size_t)blockIdx.x*128 + t]      = spA[t]+spA[t+64];
    part[(size_t)blockIdx.x*128 + 64 + t] = spQ[t]+spQ[t+64];
  }
}

// ---------------------------------------------------------------------------
// MLP layer 2: z -> BN1+relu -> @W2^T + b2 -> z (in place, f32), partials.
// ---------------------------------------------------------------------------
__global__ __launch_bounds__(128) void mlp2_kernel(
    float* __restrict__ z, const float* __restrict__ ab1,
    const float* __restrict__ W2, const float* __restrict__ b2,
    float* __restrict__ part)
{
  __shared__ float wl[67*64];
  __shared__ float spA[128], spQ[128];
  __shared__ float s_ab[128];
  const int t = threadIdx.x;
  const int m = blockIdx.x*128 + t;
  for (int e=t; e<64*64; e+=128){
    int o = e>>6, c = e&63;
    wl[c*64+o] = W2[e];
  }
  if (t<128) s_ab[t] = ab1[t];
  __syncthreads();
  float* zr = z + (size_t)m*64;
  float f[64];
  #pragma unroll
  for (int q=0;q<16;q++){
    float4 v = *(const float4*)(zr + q*4);
    float a0 = __fmaf_rn(v.x, s_ab[q*4+0], s_ab[64+q*4+0]);
    float a1 = __fmaf_rn(v.y, s_ab[q*4+1], s_ab[64+q*4+1]);
    float a2 = __fmaf_rn(v.z, s_ab[q*4+2], s_ab[64+q*4+2]);
    float a3 = __fmaf_rn(v.w, s_ab[q*4+3], s_ab[64+q*4+3]);
    f[q*4+0] = a0 > 0.f ? a0 : 0.f;
    f[q*4+1] = a1 > 0.f ? a1 : 0.f;
    f[q*4+2] = a2 > 0.f ? a2 : 0.f;
    f[q*4+3] = a3 > 0.f ? a3 : 0.f;
  }
  float acc[64];
  #pragma unroll
  for (int o=0;o<64;o++) acc[o]=0.0f;
  #pragma unroll
  for (int c=0;c<64;c++){
    const float fc = f[c];
    const float* wr = &wl[c*64];
    #pragma unroll
    for (int q=0;q<16;q++){
      float4 w = *(const float4*)(wr + q*4);
      acc[q*4+0] = __fmaf_rn(fc, w.x, acc[q*4+0]);
      acc[q*4+1] = __fmaf_rn(fc, w.y, acc[q*4+1]);
      acc[q*4+2] = __fmaf_rn(fc, w.z, acc[q*4+2]);
      acc[q*4+3] = __fmaf_rn(fc, w.w, acc[q*4+3]);
    }
  }
  #pragma unroll
  for (int o=0;o<64;o++) acc[o] = __fadd_rn(acc[o], b2[o]);
  #pragma unroll
  for (int q=0;q<16;q++){
    float4 v; v.x=acc[q*4]; v.y=acc[q*4+1]; v.z=acc[q*4+2]; v.w=acc[q*4+3];
    *(float4*)(zr + q*4) = v;
  }
  float sA=0.f, sQ=0.f;
  const int oc = t & 63;
  for (int p=0;p<2;p++){
    __syncthreads();
    if ((t>>6)==p){
      const int r = t & 63;
      #pragma unroll
      for (int j=0;j<64;j++) wl[r*65+j] = acc[j];
    }
    __syncthreads();
    const int r0 = (t>>6)*32;
    for (int r=r0; r<r0+32; r++){
      float v = wl[r*65+oc];
      sA += v; sQ = __fmaf_rn(v,v,sQ);
    }
  }
  spA[t]=sA; spQ[t]=sQ;
  __syncthreads();
  if (t<64){
    part[(size_t)blockIdx.x*128 + t]      = spA[t]+spA[t+64];
    part[(size_t)blockIdx.x*128 + 64 + t] = spQ[t]+spQ[t+64];
  }
}

// ---------------------------------------------------------------------------
// MLP layer 3 + group max: 256 thr = 128 samples x 2 halves (64 outs each).
// ---------------------------------------------------------------------------
__global__ __launch_bounds__(256) void mlp3_kernel(
    const float* __restrict__ z, const float* __restrict__ ab2,
    const float* __restrict__ W3, const float* __restrict__ b3,
    float* __restrict__ gmax, float* __restrict__ part)
{
  __shared__ float wl[128*65];       // union: W (64*128=8192) / stats (128*65)
  __shared__ float spA[256], spQ[256];
  __shared__ float s_ab[128];
  const int t = threadIdx.x;
  const int m0 = blockIdx.x*128;
  const int sm = t>>1, h = t&1;
  const int m = m0 + sm;
  for (int e=t; e<64*128; e+=256){
    int o = e>>6, c = e&63;
    wl[c*128+o] = W3[e];
  }
  if (t<128) s_ab[t] = ab2[t];
  __syncthreads();
  const float* zr = z + (size_t)m*64;
  float f[64];
  #pragma unroll
  for (int q=0;q<16;q++){
    float4 v = *(const float4*)(zr + q*4);
    float a0 = __fmaf_rn(v.x, s_ab[q*4+0], s_ab[64+q*4+0]);
    float a1 = __fmaf_rn(v.y, s_ab[q*4+1], s_ab[64+q*4+1]);
    float a2 = __fmaf_rn(v.z, s_ab[q*4+2], s_ab[64+q*4+2]);
    float a3 = __fmaf_rn(v.w, s_ab[q*4+3], s_ab[64+q*4+3]);
    f[q*4+0] = a0 > 0.f ? a0 : 0.f;
    f[q*4+1] = a1 > 0.f ? a1 : 0.f;
    f[q*4+2] = a2 > 0.f ? a2 : 0.f;
    f[q*4+3] = a3 > 0.f ? a3 : 0.f;
  }
  float acc[64];
  #pragma unroll
  for (int o=0;o<64;o++) acc[o]=0.0f;
  #pragma unroll
  for (int c=0;c<64;c++){
    const float fc = f[c];
    const float* wr = &wl[c*128 + h*64];
    #pragma unroll
    for (int q=0;q<16;q++){
      float4 w = *(const float4*)(wr + q*4);
      acc[q*4+0] = __fmaf_rn(fc, w.x, acc[q*4+0]);
      acc[q*4+1] = __fmaf_rn(fc, w.y, acc[q*4+1]);
      acc[q*4+2] = __fmaf_rn(fc, w.z, acc[q*4+2]);
      acc[q*4+3] = __fmaf_rn(fc, w.w, acc[q*4+3]);
    }
  }
  #pragma unroll
  for (int j=0;j<64;j++) acc[j] = __fadd_rn(acc[j], b3[h*64+j]);
  // BN3 partial sums over ALL samples (pre-max), per half-pass
  for (int p=0;p<2;p++){
    __syncthreads();
    if (h==p){
      const int r = sm;
      #pragma unroll
      for (int j=0;j<64;j++) wl[r*65+j] = acc[j];
    }
    __syncthreads();
    const int oc = t & 63;
    const int q4 = t >> 6;
    float sA=0.f, sQ=0.f;
    for (int r=q4*32; r<q4*32+32; r++){
      float v = wl[r*65+oc];
      sA += v; sQ = __fmaf_rn(v,v,sQ);
    }
    spA[t]=sA; spQ[t]=sQ;
    __syncthreads();
    if (t<64){
      float A = spA[t]+spA[t+64]+spA[t+128]+spA[t+192];
      float Q = spQ[t]+spQ[t+64]+spQ[t+128]+spQ[t+192];
      part[(size_t)blockIdx.x*256 + p*64 + t]       = A;
      part[(size_t)blockIdx.x*256 + 128 + p*64 + t] = Q;
    }
  }
  // group max over the wave's 32 samples (even/odd lanes hold the two halves)
  #pragma unroll
  for (int off=2; off<64; off<<=1){
    #pragma unroll
    for (int j=0;j<64;j++){
      float ov = __shfl_xor(acc[j], off, 64);
      acc[j] = acc[j] > ov ? acc[j] : ov;
    }
  }
  const int lane = t & 63, w = t >> 6;
  const int gg = (m0>>5) + w;
  if (lane < 2){
    float* gp = gmax + (size_t)gg*128 + lane*64;
    #pragma unroll
    for (int q=0;q<16;q++){
      float4 v; v.x=acc[q*4]; v.y=acc[q*4+1]; v.z=acc[q*4+2]; v.w=acc[q*4+3];
      *(float4*)(gp + q*4) = v;
    }
  }
}

// ---------------------------------------------------------------------------
// BN stats finalize: ab[o]=g/sqrt(var+eps), ab[cout+o]=be-mean*a
// ---------------------------------------------------------------------------
__global__ __launch_bounds__(64) void reduce_kernel(const float* __restrict__ part,
    const float* __restrict__ gw, const float* __restrict__ bew,
    float* __restrict__ ab, int cout, int nblk)
{
  const int o = blockIdx.x, t = threadIdx.x;
  const int stride = 2*cout;
  float A=0.f, Q=0.f;
  for (int i=t;i<nblk;i+=64){
    A += part[(size_t)i*stride + o];
    Q += part[(size_t)i*stride + cout + o];
  }
  #pragma unroll
  for (int off=1; off<64; off<<=1){
    A += __shfl_xor(A, off, 64);
    Q += __shfl_xor(Q, off, 64);
  }
  if (t==0){
    const float inv = 1.0f/524288.0f;
    float mean = A*inv;
    float var  = Q*inv - mean*mean;
    float a = gw[o] / sqrtf(var + 1e-5f);
    ab[o] = a;
    ab[cout+o] = bew[o] - mean*a;
  }
}

// ---------------------------------------------------------------------------
// Final: out_points[b][o][s] = relu(gmax*a3 + shift3), transposed via LDS tile
// ---------------------------------------------------------------------------
__global__ __launch_bounds__(256) void final_kernel(const float* __restrict__ gmax,
    const float* __restrict__ ab3, float* __restrict__ out)
{
  __shared__ float tile[32*129];
  __shared__ float s_a[128], s_b[128];
  const int t = threadIdx.x;
  const int b = blockIdx.x >> 6;
  const int s0 = (blockIdx.x & 63)*32;
  if (t<128){ s_a[t]=ab3[t]; s_b[t]=ab3[128+t]; }
  const float* gp = gmax + ((size_t)b*NPOINT + s0)*128;
  for (int e=t; e<32*32; e+=256){
    int r = e>>5, q = e&31;
    float4 v = *(const float4*)(gp + r*128 + q*4);
    tile[r*129 + q*4+0]=v.x; tile[r*129 + q*4+1]=v.y;
    tile[r*129 + q*4+2]=v.z; tile[r*129 + q*4+3]=v.w;
  }
  __syncthreads();
  float* ob = out + 49152 + (size_t)b*128*NPOINT;
  for (int e=t; e<128*32; e+=256){
    int o = e>>5, ls = e&31;
    float v = tile[ls*129 + o];
    v = __fmaf_rn(v, s_a[o], s_b[o]);
    v = v > 0.f ? v : 0.f;
    ob[(size_t)o*NPOINT + s0 + ls] = v;
  }
}

extern "C" void kernel_launch(void* const* d_in, const int* in_sizes, int n_in,
                              void* d_out, int out_size, void* d_ws, size_t ws_size,
                              hipStream_t stream)
{
  const float* xyz    = (const float*)d_in[0];
  const float* points = (const float*)d_in[1];
  const float* W1 = (const float*)d_in[2];
  const float* b1 = (const float*)d_in[3];
  const float* g1 = (const float*)d_in[4];
  const float* be1= (const float*)d_in[5];
  const float* W2 = (const float*)d_in[6];
  const float* b2 = (const float*)d_in[7];
  const float* g2 = (const float*)d_in[8];
  const float* be2= (const float*)d_in[9];
  const float* W3 = (const float*)d_in[10];
  const float* b3 = (const float*)d_in[11];
  const float* g3 = (const float*)d_in[12];
  const float* be3= (const float*)d_in[13];
  float* out = (float*)d_out;
  char* ws = (char*)d_ws;
  // ws layout (bytes), f32 z end-to-end (~153 MB total):
  float* z     = (float*)(ws);                            // 134,217,728
  float* gmax  = (float*)(ws + 134217728);                //   8,388,608
  int*   ball  = (int*)  (ws + 142606336);                //   2,097,152
  float* part1 = (float*)(ws + 144703488);                //   2,097,152
  float* part2 = (float*)(ws + 146800640);                //   2,097,152
  float* part3 = (float*)(ws + 148897792);                //   4,194,304
  float* ab1   = (float*)(ws + 153092096);                //   512
  float* ab2   = (float*)(ws + 153092608);                //   512
  float* ab3   = (float*)(ws + 153093120);                //   1024

  hipLaunchKernelGGL(fps_kernel,   dim3(NB),   dim3(1024), 0, stream, xyz, out);
  hipLaunchKernelGGL(ball_kernel,  dim3(4096), dim3(256),  0, stream, xyz, out, ball);
  hipLaunchKernelGGL(mlp1_kernel,  dim3(4096), dim3(128),  0, stream, xyz, points, out, ball, W1, b1, z, part1);
  hipLaunchKernelGGL(reduce_kernel,dim3(64),   dim3(64),   0, stream, part1, g1, be1, ab1, 64, 4096);
  hipLaunchKernelGGL(mlp2_kernel,  dim3(4096), dim3(128),  0, stream, z, ab1, W2, b2, part2);
  hipLaunchKernelGGL(reduce_kernel,dim3(64),   dim3(64),   0, stream, part2, g2, be2, ab2, 64, 4096);
  hipLaunchKernelGGL(mlp3_kernel,  dim3(4096), dim3(256),  0, stream, z, ab2, W3, b3, gmax, part3);
  hipLaunchKernelGGL(reduce_kernel,dim3(128),  dim3(64),   0, stream, part3, g3, be3, ab3, 128, 4096);
  hipLaunchKernelGGL(final_kernel, dim3(512),  dim3(256),  0, stream, gmax, ab3, out);
}

// Round 5
// 3227.821 us; speedup vs baseline: 1.1476x; 1.1476x over previous
//
#include <hip/hip_runtime.h>
#include <hip/hip_bf16.h>
#include <stdint.h>

#define NB 8
#define NPTS 8192
#define NCH 64
#define NPOINT 2048
#define NSAMPLE 32
#define R2 0.04f

// ---------------------------------------------------------------------------
// FPS: one block (512 thr = 8 waves) per batch. Exact IEEE replication of
//   d = ((dx*dx + dy*dy) + dz*dz);  dist = min(dist, d);  argmax (first index)
// Single barrier per step: per-wave shfl-reduce -> LDS key -> all waves
// redundantly reduce the 8 keys. Key packs (dist_bits<<13)|(8191-idx) so
// max == largest dist, ties -> smallest index (jnp.argmax semantics).
// Key slots double-buffered by step parity -> one barrier is race-free.
// ---------------------------------------------------------------------------
__global__ __launch_bounds__(512) void fps_kernel(const float* __restrict__ xyz,
                                                  float* __restrict__ out)
{
  const int t = threadIdx.x;
  const int wv = t >> 6, lane = t & 63;
  const int b = blockIdx.x;
  const float* xb = xyz + (size_t)b*3*NPTS;
  // lane owns points idx = wv*1024 + k*64 + lane (coalesced load, k ascending
  // => idx ascending => strict-> keeps first index within lane)
  float px[16], py[16], pz[16], dist[16];
  const int base = (wv<<10) + lane;
  #pragma unroll
  for (int k=0;k<16;k++){
    int i = base + (k<<6);
    px[k]=xb[i]; py[k]=xb[NPTS+i]; pz[k]=xb[2*NPTS+i];
    dist[k]=1e10f;
  }
  __shared__ unsigned long long s_key[2][8];
  float cx = xb[0], cy = xb[NPTS], cz = xb[2*NPTS];   // far_0 = 0
  float* oxb = out + (size_t)b*3*NPOINT;
  for (int s=0;s<NPOINT;s++){
    if (t==0){ oxb[s]=cx; oxb[NPOINT+s]=cy; oxb[2*NPOINT+s]=cz; }
    float best = -1.0f; int bidx = 0;
    #pragma unroll
    for (int k=0;k<16;k++){
      float dx=__fsub_rn(px[k],cx), dy=__fsub_rn(py[k],cy), dz=__fsub_rn(pz[k],cz);
      float d = __fadd_rn(__fadd_rn(__fmul_rn(dx,dx),__fmul_rn(dy,dy)),__fmul_rn(dz,dz));
      float nd = d < dist[k] ? d : dist[k];
      dist[k]=nd;
      if (nd > best){ best = nd; bidx = base + (k<<6); }
    }
    // best >= 0 always -> float bits order-preserving
    unsigned long long key = ((unsigned long long)__float_as_uint(best) << 13)
                           | (unsigned long long)(8191 - bidx);
    #pragma unroll
    for (int off=1; off<64; off<<=1){
      unsigned long long ok = __shfl_xor(key, off, 64);
      if (ok > key) key = ok;
    }
    if (lane==0) s_key[s&1][wv] = key;
    __syncthreads();
    const unsigned long long* kr = s_key[s&1];
    unsigned long long k0=kr[0],k1=kr[1],k2=kr[2],k3=kr[3],
                       k4=kr[4],k5=kr[5],k6=kr[6],k7=kr[7];
    unsigned long long m01=k0>k1?k0:k1, m23=k2>k3?k2:k3;
    unsigned long long m45=k4>k5?k4:k5, m67=k6>k7?k6:k7;
    unsigned long long m03=m01>m23?m01:m23, m47=m45>m67?m45:m67;
    unsigned long long mk = m03>m47?m03:m47;
    const int far = 8191 - (int)(mk & 8191ull);
    // uniform (broadcast) global load of next centroid — L2-resident
    cx = xb[far]; cy = xb[NPTS+far]; cz = xb[2*NPTS+far];
  }
}

// ---------------------------------------------------------------------------
// Ball query: one wave per (b,s).
//   dot  = fma(z,z', fma(y,y', x*x'))      <- GEMM-path semantics (FMA chain)
//   csum/dsum = (x²+y²)+z² separate mul/add <- elementwise+reduce semantics
//   sqr  = ((-2*dot) + csum) + dsum ; keep iff !(sqr > 0.04f)
// ---------------------------------------------------------------------------
__global__ __launch_bounds__(256) void ball_kernel(const float* __restrict__ xyz,
                                                   const float* __restrict__ nxyz,
                                                   int* __restrict__ ball_idx)
{
  __shared__ int s_buf[4][NSAMPLE];
  const int wv = threadIdx.x >> 6, lane = threadIdx.x & 63;
  const int g = blockIdx.x*4 + wv;
  const int b = g >> 11;
  const int s = g & 2047;
  const float* ob = nxyz + (size_t)b*3*NPOINT;
  const float cx = ob[s], cy = ob[NPOINT+s], cz = ob[2*NPOINT+s];
  const float csum = __fadd_rn(__fadd_rn(__fmul_rn(cx,cx),__fmul_rn(cy,cy)),__fmul_rn(cz,cz));
  const float* xb = xyz + (size_t)b*3*NPTS;
  int cnt = 0;
  for (int c0=0; c0<NPTS; c0+=64){
    const int i = c0 + lane;
    float x=xb[i], y=xb[NPTS+i], z=xb[2*NPTS+i];
    float dot  = __fmaf_rn(cz, z, __fmaf_rn(cy, y, __fmul_rn(cx, x)));
    float dsum = __fadd_rn(__fadd_rn(__fmul_rn(x,x),__fmul_rn(y,y)),__fmul_rn(z,z));
    float sqr  = __fadd_rn(__fadd_rn(__fmul_rn(-2.0f,dot), csum), dsum);
    bool in = (sqr <= R2);
    unsigned long long m = __ballot(in);
    int rank = cnt + __popcll(m & ((1ull<<lane)-1ull));
    if (in && rank < NSAMPLE) s_buf[wv][rank] = i;
    cnt += (int)__popcll(m);
    if (cnt >= NSAMPLE) break;
  }
  const int first = s_buf[wv][0];
  if (lane < NSAMPLE){
    int v = (lane < cnt) ? s_buf[wv][lane] : first;
    ball_idx[(size_t)g*NSAMPLE + lane] = v;
  }
}

// ---------------------------------------------------------------------------
// MLP layer 1: gather (3 norm + 64 point channels) -> z1 = feat@W1^T + b1
// f32 z out, per-block BN partials.
// ---------------------------------------------------------------------------
__global__ __launch_bounds__(128) void mlp1_kernel(
    const float* __restrict__ xyz, const float* __restrict__ points,
    const float* __restrict__ nxyz, const int* __restrict__ ball_idx,
    const float* __restrict__ W1, const float* __restrict__ b1,
    float* __restrict__ z, float* __restrict__ part)
{
  __shared__ float wl[67*64];        // union: W (67*64) / stats tile (64*65)
  __shared__ float spA[128], spQ[128];
  const int t = threadIdx.x;
  const int m = blockIdx.x*128 + t;
  const int g = m >> 5;
  const int b = g >> 11;
  const int s = g & 2047;
  for (int e=t; e<67*64; e+=128){
    int o = e/67, c = e - o*67;
    wl[c*64+o] = W1[e];
  }
  const int idx = ball_idx[m];
  const float* xb = xyz + (size_t)b*3*NPTS;
  const float* ob = nxyz + (size_t)b*3*NPOINT;
  float f[67];
  f[0] = __fsub_rn(xb[idx],        ob[s]);
  f[1] = __fsub_rn(xb[NPTS+idx],   ob[NPOINT+s]);
  f[2] = __fsub_rn(xb[2*NPTS+idx], ob[2*NPOINT+s]);
  const float* pb = points + (size_t)b*NCH*NPTS;
  #pragma unroll
  for (int c=0;c<64;c++) f[3+c] = pb[(size_t)c*NPTS + idx];
  __syncthreads();
  float acc[64];
  #pragma unroll
  for (int o=0;o<64;o++) acc[o]=0.0f;
  #pragma unroll
  for (int c=0;c<67;c++){
    const float fc = f[c];
    const float* wr = &wl[c*64];
    #pragma unroll
    for (int q=0;q<16;q++){
      float4 w = *(const float4*)(wr + q*4);
      acc[q*4+0] = __fmaf_rn(fc, w.x, acc[q*4+0]);
      acc[q*4+1] = __fmaf_rn(fc, w.y, acc[q*4+1]);
      acc[q*4+2] = __fmaf_rn(fc, w.z, acc[q*4+2]);
      acc[q*4+3] = __fmaf_rn(fc, w.w, acc[q*4+3]);
    }
  }
  #pragma unroll
  for (int o=0;o<64;o++) acc[o] = __fadd_rn(acc[o], b1[o]);
  float* zr = z + (size_t)m*64;
  #pragma unroll
  for (int q=0;q<16;q++){
    float4 v; v.x=acc[q*4]; v.y=acc[q*4+1]; v.z=acc[q*4+2]; v.w=acc[q*4+3];
    *(float4*)(zr + q*4) = v;
  }
  // BN partial sums (two half-passes reusing wl)
  float sA=0.f, sQ=0.f;
  const int oc = t & 63;
  for (int p=0;p<2;p++){
    __syncthreads();
    if ((t>>6)==p){
      const int r = t & 63;
      #pragma unroll
      for (int j=0;j<64;j++) wl[r*65+j] = acc[j];
    }
    __syncthreads();
    const int r0 = (t>>6)*32;
    for (int r=r0; r<r0+32; r++){
      float v = wl[r*65+oc];
      sA += v; sQ = __fmaf_rn(v,v,sQ);
    }
  }
  spA[t]=sA; spQ[t]=sQ;
  __syncthreads();
  if (t<64){
    part[(size_t)blockIdx.x*128 + t]      = spA[t]+spA[t+64];
    part[(size_t)blockIdx.x*128 + 64 + t] = spQ[t]+spQ[t+64];
  }
}

// ---------------------------------------------------------------------------
// MLP layer 2: z -> BN1+relu -> @W2^T + b2 -> z (in place, f32), partials.
// ---------------------------------------------------------------------------
__global__ __launch_bounds__(128) void mlp2_kernel(
    float* __restrict__ z, const float* __restrict__ ab1,
    const float* __restrict__ W2, const float* __restrict__ b2,
    float* __restrict__ part)
{
  __shared__ float wl[67*64];
  __shared__ float spA[128], spQ[128];
  __shared__ float s_ab[128];
  const int t = threadIdx.x;
  const int m = blockIdx.x*128 + t;
  for (int e=t; e<64*64; e+=128){
    int o = e>>6, c = e&63;
    wl[c*64+o] = W2[e];
  }
  if (t<128) s_ab[t] = ab1[t];
  __syncthreads();
  float* zr = z + (size_t)m*64;
  float f[64];
  #pragma unroll
  for (int q=0;q<16;q++){
    float4 v = *(const float4*)(zr + q*4);
    float a0 = __fmaf_rn(v.x, s_ab[q*4+0], s_ab[64+q*4+0]);
    float a1 = __fmaf_rn(v.y, s_ab[q*4+1], s_ab[64+q*4+1]);
    float a2 = __fmaf_rn(v.z, s_ab[q*4+2], s_ab[64+q*4+2]);
    float a3 = __fmaf_rn(v.w, s_ab[q*4+3], s_ab[64+q*4+3]);
    f[q*4+0] = a0 > 0.f ? a0 : 0.f;
    f[q*4+1] = a1 > 0.f ? a1 : 0.f;
    f[q*4+2] = a2 > 0.f ? a2 : 0.f;
    f[q*4+3] = a3 > 0.f ? a3 : 0.f;
  }
  float acc[64];
  #pragma unroll
  for (int o=0;o<64;o++) acc[o]=0.0f;
  #pragma unroll
  for (int c=0;c<64;c++){
    const float fc = f[c];
    const float* wr = &wl[c*64];
    #pragma unroll
    for (int q=0;q<16;q++){
      float4 w = *(const float4*)(wr + q*4);
      acc[q*4+0] = __fmaf_rn(fc, w.x, acc[q*4+0]);
      acc[q*4+1] = __fmaf_rn(fc, w.y, acc[q*4+1]);
      acc[q*4+2] = __fmaf_rn(fc, w.z, acc[q*4+2]);
      acc[q*4+3] = __fmaf_rn(fc, w.w, acc[q*4+3]);
    }
  }
  #pragma unroll
  for (int o=0;o<64;o++) acc[o] = __fadd_rn(acc[o], b2[o]);
  #pragma unroll
  for (int q=0;q<16;q++){
    float4 v; v.x=acc[q*4]; v.y=acc[q*4+1]; v.z=acc[q*4+2]; v.w=acc[q*4+3];
    *(float4*)(zr + q*4) = v;
  }
  float sA=0.f, sQ=0.f;
  const int oc = t & 63;
  for (int p=0;p<2;p++){
    __syncthreads();
    if ((t>>6)==p){
      const int r = t & 63;
      #pragma unroll
      for (int j=0;j<64;j++) wl[r*65+j] = acc[j];
    }
    __syncthreads();
    const int r0 = (t>>6)*32;
    for (int r=r0; r<r0+32; r++){
      float v = wl[r*65+oc];
      sA += v; sQ = __fmaf_rn(v,v,sQ);
    }
  }
  spA[t]=sA; spQ[t]=sQ;
  __syncthreads();
  if (t<64){
    part[(size_t)blockIdx.x*128 + t]      = spA[t]+spA[t+64];
    part[(size_t)blockIdx.x*128 + 64 + t] = spQ[t]+spQ[t+64];
  }
}

// ---------------------------------------------------------------------------
// MLP layer 3 + group max: 256 thr = 128 samples x 2 halves (64 outs each).
// ---------------------------------------------------------------------------
__global__ __launch_bounds__(256) void mlp3_kernel(
    const float* __restrict__ z, const float* __restrict__ ab2,
    const float* __restrict__ W3, const float* __restrict__ b3,
    float* __restrict__ gmax, float* __restrict__ part)
{
  __shared__ float wl[128*65];       // union: W (64*128=8192) / stats (128*65)
  __shared__ float spA[256], spQ[256];
  __shared__ float s_ab[128];
  const int t = threadIdx.x;
  const int m0 = blockIdx.x*128;
  const int sm = t>>1, h = t&1;
  const int m = m0 + sm;
  for (int e=t; e<64*128; e+=256){
    int o = e>>6, c = e&63;
    wl[c*128+o] = W3[e];
  }
  if (t<128) s_ab[t] = ab2[t];
  __syncthreads();
  const float* zr = z + (size_t)m*64;
  float f[64];
  #pragma unroll
  for (int q=0;q<16;q++){
    float4 v = *(const float4*)(zr + q*4);
    float a0 = __fmaf_rn(v.x, s_ab[q*4+0], s_ab[64+q*4+0]);
    float a1 = __fmaf_rn(v.y, s_ab[q*4+1], s_ab[64+q*4+1]);
    float a2 = __fmaf_rn(v.z, s_ab[q*4+2], s_ab[64+q*4+2]);
    float a3 = __fmaf_rn(v.w, s_ab[q*4+3], s_ab[64+q*4+3]);
    f[q*4+0] = a0 > 0.f ? a0 : 0.f;
    f[q*4+1] = a1 > 0.f ? a1 : 0.f;
    f[q*4+2] = a2 > 0.f ? a2 : 0.f;
    f[q*4+3] = a3 > 0.f ? a3 : 0.f;
  }
  float acc[64];
  #pragma unroll
  for (int o=0;o<64;o++) acc[o]=0.0f;
  #pragma unroll
  for (int c=0;c<64;c++){
    const float fc = f[c];
    const float* wr = &wl[c*128 + h*64];
    #pragma unroll
    for (int q=0;q<16;q++){
      float4 w = *(const float4*)(wr + q*4);
      acc[q*4+0] = __fmaf_rn(fc, w.x, acc[q*4+0]);
      acc[q*4+1] = __fmaf_rn(fc, w.y, acc[q*4+1]);
      acc[q*4+2] = __fmaf_rn(fc, w.z, acc[q*4+2]);
      acc[q*4+3] = __fmaf_rn(fc, w.w, acc[q*4+3]);
    }
  }
  #pragma unroll
  for (int j=0;j<64;j++) acc[j] = __fadd_rn(acc[j], b3[h*64+j]);
  // BN3 partial sums over ALL samples (pre-max), per half-pass
  for (int p=0;p<2;p++){
    __syncthreads();
    if (h==p){
      const int r = sm;
      #pragma unroll
      for (int j=0;j<64;j++) wl[r*65+j] = acc[j];
    }
    __syncthreads();
    const int oc = t & 63;
    const int q4 = t >> 6;
    float sA=0.f, sQ=0.f;
    for (int r=q4*32; r<q4*32+32; r++){
      float v = wl[r*65+oc];
      sA += v; sQ = __fmaf_rn(v,v,sQ);
    }
    spA[t]=sA; spQ[t]=sQ;
    __syncthreads();
    if (t<64){
      float A = spA[t]+spA[t+64]+spA[t+128]+spA[t+192];
      float Q = spQ[t]+spQ[t+64]+spQ[t+128]+spQ[t+192];
      part[(size_t)blockIdx.x*256 + p*64 + t]       = A;
      part[(size_t)blockIdx.x*256 + 128 + p*64 + t] = Q;
    }
  }
  // group max over the wave's 32 samples (even/odd lanes hold the two halves)
  #pragma unroll
  for (int off=2; off<64; off<<=1){
    #pragma unroll
    for (int j=0;j<64;j++){
      float ov = __shfl_xor(acc[j], off, 64);
      acc[j] = acc[j] > ov ? acc[j] : ov;
    }
  }
  const int lane = t & 63, w = t >> 6;
  const int gg = (m0>>5) + w;
  if (lane < 2){
    float* gp = gmax + (size_t)gg*128 + lane*64;
    #pragma unroll
    for (int q=0;q<16;q++){
      float4 v; v.x=acc[q*4]; v.y=acc[q*4+1]; v.z=acc[q*4+2]; v.w=acc[q*4+3];
      *(float4*)(gp + q*4) = v;
    }
  }
}

// ---------------------------------------------------------------------------
// BN stats finalize: ab[o]=g/sqrt(var+eps), ab[cout+o]=be-mean*a
// ---------------------------------------------------------------------------
__global__ __launch_bounds__(64) void reduce_kernel(const float* __restrict__ part,
    const float* __restrict__ gw, const float* __restrict__ bew,
    float* __restrict__ ab, int cout, int nblk)
{
  const int o = blockIdx.x, t = threadIdx.x;
  const int stride = 2*cout;
  float A=0.f, Q=0.f;
  for (int i=t;i<nblk;i+=64){
    A += part[(size_t)i*stride + o];
    Q += part[(size_t)i*stride + cout + o];
  }
  #pragma unroll
  for (int off=1; off<64; off<<=1){
    A += __shfl_xor(A, off, 64);
    Q += __shfl_xor(Q, off, 64);
  }
  if (t==0){
    const float inv = 1.0f/524288.0f;
    float mean = A*inv;
    float var  = Q*inv - mean*mean;
    float a = gw[o] / sqrtf(var + 1e-5f);
    ab[o] = a;
    ab[cout+o] = bew[o] - mean*a;
  }
}

// ---------------------------------------------------------------------------
// Final: out_points[b][o][s] = relu(gmax*a3 + shift3), transposed via LDS tile
// ---------------------------------------------------------------------------
__global__ __launch_bounds__(256) void final_kernel(const float* __restrict__ gmax,
    const float* __restrict__ ab3, float* __restrict__ out)
{
  __shared__ float tile[32*129];
  __shared__ float s_a[128], s_b[128];
  const int t = threadIdx.x;
  const int b = blockIdx.x >> 6;
  const int s0 = (blockIdx.x & 63)*32;
  if (t<128){ s_a[t]=ab3[t]; s_b[t]=ab3[128+t]; }
  const float* gp = gmax + ((size_t)b*NPOINT + s0)*128;
  for (int e=t; e<32*32; e+=256){
    int r = e>>5, q = e&31;
    float4 v = *(const float4*)(gp + r*128 + q*4);
    tile[r*129 + q*4+0]=v.x; tile[r*129 + q*4+1]=v.y;
    tile[r*129 + q*4+2]=v.z; tile[r*129 + q*4+3]=v.w;
  }
  __syncthreads();
  float* ob = out + 49152 + (size_t)b*128*NPOINT;
  for (int e=t; e<128*32; e+=256){
    int o = e>>5, ls = e&31;
    float v = tile[ls*129 + o];
    v = __fmaf_rn(v, s_a[o], s_b[o]);
    v = v > 0.f ? v : 0.f;
    ob[(size_t)o*NPOINT + s0 + ls] = v;
  }
}

extern "C" void kernel_launch(void* const* d_in, const int* in_sizes, int n_in,
                              void* d_out, int out_size, void* d_ws, size_t ws_size,
                              hipStream_t stream)
{
  const float* xyz    = (const float*)d_in[0];
  const float* points = (const float*)d_in[1];
  const float* W1 = (const float*)d_in[2];
  const float* b1 = (const float*)d_in[3];
  const float* g1 = (const float*)d_in[4];
  const float* be1= (const float*)d_in[5];
  const float* W2 = (const float*)d_in[6];
  const float* b2 = (const float*)d_in[7];
  const float* g2 = (const float*)d_in[8];
  const float* be2= (const float*)d_in[9];
  const float* W3 = (const float*)d_in[10];
  const float* b3 = (const float*)d_in[11];
  const float* g3 = (const float*)d_in[12];
  const float* be3= (const float*)d_in[13];
  float* out = (float*)d_out;
  char* ws = (char*)d_ws;
  // ws layout (bytes), f32 z end-to-end (~153 MB total):
  float* z     = (float*)(ws);                            // 134,217,728
  float* gmax  = (float*)(ws + 134217728);                //   8,388,608
  int*   ball  = (int*)  (ws + 142606336);                //   2,097,152
  float* part1 = (float*)(ws + 144703488);                //   2,097,152
  float* part2 = (float*)(ws + 146800640);                //   2,097,152
  float* part3 = (float*)(ws + 148897792);                //   4,194,304
  float* ab1   = (float*)(ws + 153092096);                //   512
  float* ab2   = (float*)(ws + 153092608);                //   512
  float* ab3   = (float*)(ws + 153093120);                //   1024

  hipLaunchKernelGGL(fps_kernel,   dim3(NB),   dim3(512),  0, stream, xyz, out);
  hipLaunchKernelGGL(ball_kernel,  dim3(4096), dim3(256),  0, stream, xyz, out, ball);
  hipLaunchKernelGGL(mlp1_kernel,  dim3(4096), dim3(128),  0, stream, xyz, points, out, ball, W1, b1, z, part1);
  hipLaunchKernelGGL(reduce_kernel,dim3(64),   dim3(64),   0, stream, part1, g1, be1, ab1, 64, 4096);
  hipLaunchKernelGGL(mlp2_kernel,  dim3(4096), dim3(128),  0, stream, z, ab1, W2, b2, part2);
  hipLaunchKernelGGL(reduce_kernel,dim3(64),   dim3(64),   0, stream, part2, g2, be2, ab2, 64, 4096);
  hipLaunchKernelGGL(mlp3_kernel,  dim3(4096), dim3(256),  0, stream, z, ab2, W3, b3, gmax, part3);
  hipLaunchKernelGGL(reduce_kernel,dim3(128),  dim3(64),   0, stream, part3, g3, be3, ab3, 128, 4096);
  hipLaunchKernelGGL(final_kernel, dim3(512),  dim3(256),  0, stream, gmax, ab3, out);
}

// Round 6
// 2967.242 us; speedup vs baseline: 1.2484x; 1.0878x over previous
//
#include <hip/hip_runtime.h>
#include <hip/hip_bf16.h>
#include <stdint.h>

#define NB 8
#define NPTS 8192
#define NCH 64
#define NPOINT 2048
#define NSAMPLE 32
#define R2 0.04f

// u64 max with a DPP-moved partner: 2x update_dpp (32b halves) + 64b cmp/select.
// bound_ctrl=true => invalid source lanes yield 0; key>0 always so max(key,0)=key.
#define DPP_MAX_STEP(C) { \
  int lo2_ = __builtin_amdgcn_update_dpp(0, (int)(unsigned int)key, (C), 0xf, 0xf, true); \
  int hi2_ = __builtin_amdgcn_update_dpp(0, (int)(unsigned int)(key>>32), (C), 0xf, 0xf, true); \
  unsigned long long k2_ = ((unsigned long long)(unsigned int)hi2_ << 32) | (unsigned int)lo2_; \
  if (k2_ > key) key = k2_; }

// ---------------------------------------------------------------------------
// FPS: one block (512 thr = 8 waves) per batch. Exact IEEE replication of
//   d = ((dx*dx + dy*dy) + dz*dz);  dist = min(dist, d);  argmax (first index)
// Per step: per-lane scan -> u64 key (dist_bits<<13)|(8191-idx) -> DPP wave
// max (row_shr 1,2,4,8 + row_bcast 15,31; result in lane 63) -> lane 63
// prefetches its candidate's coords (overlaps barrier) -> single barrier ->
// all waves tree-max the 8 keys, wave id = far>>10, coords from LDS.
// Key slots double-buffered by step parity -> one barrier is race-free.
// ---------------------------------------------------------------------------
__global__ __launch_bounds__(512) void fps_kernel(const float* __restrict__ xyz,
                                                  float* __restrict__ out)
{
  const int t = threadIdx.x;
  const int wv = t >> 6, lane = t & 63;
  const int b = blockIdx.x;
  const float* xb = xyz + (size_t)b*3*NPTS;
  float px[16], py[16], pz[16], dist[16];
  const int base = (wv<<10) + lane;
  #pragma unroll
  for (int k=0;k<16;k++){
    int i = base + (k<<6);
    px[k]=xb[i]; py[k]=xb[NPTS+i]; pz[k]=xb[2*NPTS+i];
    dist[k]=1e10f;
  }
  __shared__ unsigned long long s_key[2][8];
  __shared__ float s_cand[2][8][3];
  float cx = xb[0], cy = xb[NPTS], cz = xb[2*NPTS];   // far_0 = 0
  float* oxb = out + (size_t)b*3*NPOINT;
  for (int s=0;s<NPOINT;s++){
    if (t==0){ oxb[s]=cx; oxb[NPOINT+s]=cy; oxb[2*NPOINT+s]=cz; }
    float best = -1.0f; int bidx = 0;
    #pragma unroll
    for (int k=0;k<16;k++){
      float dx=__fsub_rn(px[k],cx), dy=__fsub_rn(py[k],cy), dz=__fsub_rn(pz[k],cz);
      float d = __fadd_rn(__fadd_rn(__fmul_rn(dx,dx),__fmul_rn(dy,dy)),__fmul_rn(dz,dz));
      float nd = d < dist[k] ? d : dist[k];
      dist[k]=nd;
      if (nd > best){ best = nd; bidx = base + (k<<6); }   // strict > keeps first idx
    }
    // best >= 0 always -> float bits order-preserving
    unsigned long long key = ((unsigned long long)__float_as_uint(best) << 13)
                           | (unsigned long long)(8191 - bidx);
    DPP_MAX_STEP(0x111)  // row_shr:1
    DPP_MAX_STEP(0x112)  // row_shr:2
    DPP_MAX_STEP(0x114)  // row_shr:4
    DPP_MAX_STEP(0x118)  // row_shr:8
    DPP_MAX_STEP(0x142)  // row_bcast:15
    DPP_MAX_STEP(0x143)  // row_bcast:31  -> lane 63 holds wave max
    if (lane==63){
      const int widx = 8191 - (int)(key & 8191ull);
      s_key[s&1][wv] = key;
      s_cand[s&1][wv][0] = xb[widx];
      s_cand[s&1][wv][1] = xb[NPTS+widx];
      s_cand[s&1][wv][2] = xb[2*NPTS+widx];
    }
    __syncthreads();
    const unsigned long long* kr = s_key[s&1];
    unsigned long long k0=kr[0],k1=kr[1],k2=kr[2],k3=kr[3],
                       k4=kr[4],k5=kr[5],k6=kr[6],k7=kr[7];
    unsigned long long m01=k0>k1?k0:k1, m23=k2>k3?k2:k3;
    unsigned long long m45=k4>k5?k4:k5, m67=k6>k7?k6:k7;
    unsigned long long m03=m01>m23?m01:m23, m47=m45>m67?m45:m67;
    unsigned long long mk = m03>m47?m03:m47;
    const int far = 8191 - (int)(mk & 8191ull);
    const int w = far >> 10;                 // wave that owns the winner
    cx = s_cand[s&1][w][0]; cy = s_cand[s&1][w][1]; cz = s_cand[s&1][w][2];
  }
}

// ---------------------------------------------------------------------------
// Ball query: one wave per (b,s).
//   dot  = fma(z,z', fma(y,y', x*x'))      <- GEMM-path semantics (FMA chain)
//   csum/dsum = (x²+y²)+z² separate mul/add <- elementwise+reduce semantics
//   sqr  = ((-2*dot) + csum) + dsum ; keep iff !(sqr > 0.04f)
// ---------------------------------------------------------------------------
__global__ __launch_bounds__(256) void ball_kernel(const float* __restrict__ xyz,
                                                   const float* __restrict__ nxyz,
                                                   int* __restrict__ ball_idx)
{
  __shared__ int s_buf[4][NSAMPLE];
  const int wv = threadIdx.x >> 6, lane = threadIdx.x & 63;
  const int g = blockIdx.x*4 + wv;
  const int b = g >> 11;
  const int s = g & 2047;
  const float* ob = nxyz + (size_t)b*3*NPOINT;
  const float cx = ob[s], cy = ob[NPOINT+s], cz = ob[2*NPOINT+s];
  const float csum = __fadd_rn(__fadd_rn(__fmul_rn(cx,cx),__fmul_rn(cy,cy)),__fmul_rn(cz,cz));
  const float* xb = xyz + (size_t)b*3*NPTS;
  int cnt = 0;
  for (int c0=0; c0<NPTS; c0+=64){
    const int i = c0 + lane;
    float x=xb[i], y=xb[NPTS+i], z=xb[2*NPTS+i];
    float dot  = __fmaf_rn(cz, z, __fmaf_rn(cy, y, __fmul_rn(cx, x)));
    float dsum = __fadd_rn(__fadd_rn(__fmul_rn(x,x),__fmul_rn(y,y)),__fmul_rn(z,z));
    float sqr  = __fadd_rn(__fadd_rn(__fmul_rn(-2.0f,dot), csum), dsum);
    bool in = (sqr <= R2);
    unsigned long long m = __ballot(in);
    int rank = cnt + __popcll(m & ((1ull<<lane)-1ull));
    if (in && rank < NSAMPLE) s_buf[wv][rank] = i;
    cnt += (int)__popcll(m);
    if (cnt >= NSAMPLE) break;
  }
  const int first = s_buf[wv][0];
  if (lane < NSAMPLE){
    int v = (lane < cnt) ? s_buf[wv][lane] : first;
    ball_idx[(size_t)g*NSAMPLE + lane] = v;
  }
}

// ---------------------------------------------------------------------------
// MLP layer 1: gather (3 norm + 64 point channels) -> z1 = feat@W1^T + b1
// f32 z out, per-block BN partials.
// ---------------------------------------------------------------------------
__global__ __launch_bounds__(128) void mlp1_kernel(
    const float* __restrict__ xyz, const float* __restrict__ points,
    const float* __restrict__ nxyz, const int* __restrict__ ball_idx,
    const float* __restrict__ W1, const float* __restrict__ b1,
    float* __restrict__ z, float* __restrict__ part)
{
  __shared__ float wl[67*64];        // union: W (67*64) / stats tile (64*65)
  __shared__ float spA[128], spQ[128];
  const int t = threadIdx.x;
  const int m = blockIdx.x*128 + t;
  const int g = m >> 5;
  const int b = g >> 11;
  const int s = g & 2047;
  for (int e=t; e<67*64; e+=128){
    int o = e/67, c = e - o*67;
    wl[c*64+o] = W1[e];
  }
  const int idx = ball_idx[m];
  const float* xb = xyz + (size_t)b*3*NPTS;
  const float* ob = nxyz + (size_t)b*3*NPOINT;
  float f[67];
  f[0] = __fsub_rn(xb[idx],        ob[s]);
  f[1] = __fsub_rn(xb[NPTS+idx],   ob[NPOINT+s]);
  f[2] = __fsub_rn(xb[2*NPTS+idx], ob[2*NPOINT+s]);
  const float* pb = points + (size_t)b*NCH*NPTS;
  #pragma unroll
  for (int c=0;c<64;c++) f[3+c] = pb[(size_t)c*NPTS + idx];
  __syncthreads();
  float acc[64];
  #pragma unroll
  for (int o=0;o<64;o++) acc[o]=0.0f;
  #pragma unroll
  for (int c=0;c<67;c++){
    const float fc = f[c];
    const float* wr = &wl[c*64];
    #pragma unroll
    for (int q=0;q<16;q++){
      float4 w = *(const float4*)(wr + q*4);
      acc[q*4+0] = __fmaf_rn(fc, w.x, acc[q*4+0]);
      acc[q*4+1] = __fmaf_rn(fc, w.y, acc[q*4+1]);
      acc[q*4+2] = __fmaf_rn(fc, w.z, acc[q*4+2]);
      acc[q*4+3] = __fmaf_rn(fc, w.w, acc[q*4+3]);
    }
  }
  #pragma unroll
  for (int o=0;o<64;o++) acc[o] = __fadd_rn(acc[o], b1[o]);
  float* zr = z + (size_t)m*64;
  #pragma unroll
  for (int q=0;q<16;q++){
    float4 v; v.x=acc[q*4]; v.y=acc[q*4+1]; v.z=acc[q*4+2]; v.w=acc[q*4+3];
    *(float4*)(zr + q*4) = v;
  }
  // BN partial sums (two half-passes reusing wl)
  float sA=0.f, sQ=0.f;
  const int oc = t & 63;
  for (int p=0;p<2;p++){
    __syncthreads();
    if ((t>>6)==p){
      const int r = t & 63;
      #pragma unroll
      for (int j=0;j<64;j++) wl[r*65+j] = acc[j];
    }
    __syncthreads();
    const int r0 = (t>>6)*32;
    for (int r=r0; r<r0+32; r++){
      float v = wl[r*65+oc];
      sA += v; sQ = __fmaf_rn(v,v,sQ);
    }
  }
  spA[t]=sA; spQ[t]=sQ;
  __syncthreads();
  if (t<64){
    part[(size_t)blockIdx.x*128 + t]      = spA[t]+spA[t+64];
    part[(size_t)blockIdx.x*128 + 64 + t] = spQ[t]+spQ[t+64];
  }
}

// ---------------------------------------------------------------------------
// MLP layer 2: z -> BN1+relu -> @W2^T + b2 -> z (in place, f32), partials.
// ---------------------------------------------------------------------------
__global__ __launch_bounds__(128) void mlp2_kernel(
    float* __restrict__ z, const float* __restrict__ ab1,
    const float* __restrict__ W2, const float* __restrict__ b2,
    float* __restrict__ part)
{
  __shared__ float wl[67*64];
  __shared__ float spA[128], spQ[128];
  __shared__ float s_ab[128];
  const int t = threadIdx.x;
  const int m = blockIdx.x*128 + t;
  for (int e=t; e<64*64; e+=128){
    int o = e>>6, c = e&63;
    wl[c*64+o] = W2[e];
  }
  if (t<128) s_ab[t] = ab1[t];
  __syncthreads();
  float* zr = z + (size_t)m*64;
  float f[64];
  #pragma unroll
  for (int q=0;q<16;q++){
    float4 v = *(const float4*)(zr + q*4);
    float a0 = __fmaf_rn(v.x, s_ab[q*4+0], s_ab[64+q*4+0]);
    float a1 = __fmaf_rn(v.y, s_ab[q*4+1], s_ab[64+q*4+1]);
    float a2 = __fmaf_rn(v.z, s_ab[q*4+2], s_ab[64+q*4+2]);
    float a3 = __fmaf_rn(v.w, s_ab[q*4+3], s_ab[64+q*4+3]);
    f[q*4+0] = a0 > 0.f ? a0 : 0.f;
    f[q*4+1] = a1 > 0.f ? a1 : 0.f;
    f[q*4+2] = a2 > 0.f ? a2 : 0.f;
    f[q*4+3] = a3 > 0.f ? a3 : 0.f;
  }
  float acc[64];
  #pragma unroll
  for (int o=0;o<64;o++) acc[o]=0.0f;
  #pragma unroll
  for (int c=0;c<64;c++){
    const float fc = f[c];
    const float* wr = &wl[c*64];
    #pragma unroll
    for (int q=0;q<16;q++){
      float4 w = *(const float4*)(wr + q*4);
      acc[q*4+0] = __fmaf_rn(fc, w.x, acc[q*4+0]);
      acc[q*4+1] = __fmaf_rn(fc, w.y, acc[q*4+1]);
      acc[q*4+2] = __fmaf_rn(fc, w.z, acc[q*4+2]);
      acc[q*4+3] = __fmaf_rn(fc, w.w, acc[q*4+3]);
    }
  }
  #pragma unroll
  for (int o=0;o<64;o++) acc[o] = __fadd_rn(acc[o], b2[o]);
  #pragma unroll
  for (int q=0;q<16;q++){
    float4 v; v.x=acc[q*4]; v.y=acc[q*4+1]; v.z=acc[q*4+2]; v.w=acc[q*4+3];
    *(float4*)(zr + q*4) = v;
  }
  float sA=0.f, sQ=0.f;
  const int oc = t & 63;
  for (int p=0;p<2;p++){
    __syncthreads();
    if ((t>>6)==p){
      const int r = t & 63;
      #pragma unroll
      for (int j=0;j<64;j++) wl[r*65+j] = acc[j];
    }
    __syncthreads();
    const int r0 = (t>>6)*32;
    for (int r=r0; r<r0+32; r++){
      float v = wl[r*65+oc];
      sA += v; sQ = __fmaf_rn(v,v,sQ);
    }
  }
  spA[t]=sA; spQ[t]=sQ;
  __syncthreads();
  if (t<64){
    part[(size_t)blockIdx.x*128 + t]      = spA[t]+spA[t+64];
    part[(size_t)blockIdx.x*128 + 64 + t] = spQ[t]+spQ[t+64];
  }
}

// ---------------------------------------------------------------------------
// MLP layer 3 + group max: 256 thr = 128 samples x 2 halves (64 outs each).
// ---------------------------------------------------------------------------
__global__ __launch_bounds__(256) void mlp3_kernel(
    const float* __restrict__ z, const float* __restrict__ ab2,
    const float* __restrict__ W3, const float* __restrict__ b3,
    float* __restrict__ gmax, float* __restrict__ part)
{
  __shared__ float wl[128*65];       // union: W (64*128=8192) / stats (128*65)
  __shared__ float spA[256], spQ[256];
  __shared__ float s_ab[128];
  const int t = threadIdx.x;
  const int m0 = blockIdx.x*128;
  const int sm = t>>1, h = t&1;
  const int m = m0 + sm;
  for (int e=t; e<64*128; e+=256){
    int o = e>>6, c = e&63;
    wl[c*128+o] = W3[e];
  }
  if (t<128) s_ab[t] = ab2[t];
  __syncthreads();
  const float* zr = z + (size_t)m*64;
  float f[64];
  #pragma unroll
  for (int q=0;q<16;q++){
    float4 v = *(const float4*)(zr + q*4);
    float a0 = __fmaf_rn(v.x, s_ab[q*4+0], s_ab[64+q*4+0]);
    float a1 = __fmaf_rn(v.y, s_ab[q*4+1], s_ab[64+q*4+1]);
    float a2 = __fmaf_rn(v.z, s_ab[q*4+2], s_ab[64+q*4+2]);
    float a3 = __fmaf_rn(v.w, s_ab[q*4+3], s_ab[64+q*4+3]);
    f[q*4+0] = a0 > 0.f ? a0 : 0.f;
    f[q*4+1] = a1 > 0.f ? a1 : 0.f;
    f[q*4+2] = a2 > 0.f ? a2 : 0.f;
    f[q*4+3] = a3 > 0.f ? a3 : 0.f;
  }
  float acc[64];
  #pragma unroll
  for (int o=0;o<64;o++) acc[o]=0.0f;
  #pragma unroll
  for (int c=0;c<64;c++){
    const float fc = f[c];
    const float* wr = &wl[c*128 + h*64];
    #pragma unroll
    for (int q=0;q<16;q++){
      float4 w = *(const float4*)(wr + q*4);
      acc[q*4+0] = __fmaf_rn(fc, w.x, acc[q*4+0]);
      acc[q*4+1] = __fmaf_rn(fc, w.y, acc[q*4+1]);
      acc[q*4+2] = __fmaf_rn(fc, w.z, acc[q*4+2]);
      acc[q*4+3] = __fmaf_rn(fc, w.w, acc[q*4+3]);
    }
  }
  #pragma unroll
  for (int j=0;j<64;j++) acc[j] = __fadd_rn(acc[j], b3[h*64+j]);
  // BN3 partial sums over ALL samples (pre-max), per half-pass
  for (int p=0;p<2;p++){
    __syncthreads();
    if (h==p){
      const int r = sm;
      #pragma unroll
      for (int j=0;j<64;j++) wl[r*65+j] = acc[j];
    }
    __syncthreads();
    const int oc = t & 63;
    const int q4 = t >> 6;
    float sA=0.f, sQ=0.f;
    for (int r=q4*32; r<q4*32+32; r++){
      float v = wl[r*65+oc];
      sA += v; sQ = __fmaf_rn(v,v,sQ);
    }
    spA[t]=sA; spQ[t]=sQ;
    __syncthreads();
    if (t<64){
      float A = spA[t]+spA[t+64]+spA[t+128]+spA[t+192];
      float Q = spQ[t]+spQ[t+64]+spQ[t+128]+spQ[t+192];
      part[(size_t)blockIdx.x*256 + p*64 + t]       = A;
      part[(size_t)blockIdx.x*256 + 128 + p*64 + t] = Q;
    }
  }
  // group max over the wave's 32 samples (even/odd lanes hold the two halves)
  #pragma unroll
  for (int off=2; off<64; off<<=1){
    #pragma unroll
    for (int j=0;j<64;j++){
      float ov = __shfl_xor(acc[j], off, 64);
      acc[j] = acc[j] > ov ? acc[j] : ov;
    }
  }
  const int lane = t & 63, w = t >> 6;
  const int gg = (m0>>5) + w;
  if (lane < 2){
    float* gp = gmax + (size_t)gg*128 + lane*64;
    #pragma unroll
    for (int q=0;q<16;q++){
      float4 v; v.x=acc[q*4]; v.y=acc[q*4+1]; v.z=acc[q*4+2]; v.w=acc[q*4+3];
      *(float4*)(gp + q*4) = v;
    }
  }
}

// ---------------------------------------------------------------------------
// BN stats finalize: ab[o]=g/sqrt(var+eps), ab[cout+o]=be-mean*a
// ---------------------------------------------------------------------------
__global__ __launch_bounds__(64) void reduce_kernel(const float* __restrict__ part,
    const float* __restrict__ gw, const float* __restrict__ bew,
    float* __restrict__ ab, int cout, int nblk)
{
  const int o = blockIdx.x, t = threadIdx.x;
  const int stride = 2*cout;
  float A=0.f, Q=0.f;
  for (int i=t;i<nblk;i+=64){
    A += part[(size_t)i*stride + o];
    Q += part[(size_t)i*stride + cout + o];
  }
  #pragma unroll
  for (int off=1; off<64; off<<=1){
    A += __shfl_xor(A, off, 64);
    Q += __shfl_xor(Q, off, 64);
  }
  if (t==0){
    const float inv = 1.0f/524288.0f;
    float mean = A*inv;
    float var  = Q*inv - mean*mean;
    float a = gw[o] / sqrtf(var + 1e-5f);
    ab[o] = a;
    ab[cout+o] = bew[o] - mean*a;
  }
}

// ---------------------------------------------------------------------------
// Final: out_points[b][o][s] = relu(gmax*a3 + shift3), transposed via LDS tile
// ---------------------------------------------------------------------------
__global__ __launch_bounds__(256) void final_kernel(const float* __restrict__ gmax,
    const float* __restrict__ ab3, float* __restrict__ out)
{
  __shared__ float tile[32*129];
  __shared__ float s_a[128], s_b[128];
  const int t = threadIdx.x;
  const int b = blockIdx.x >> 6;
  const int s0 = (blockIdx.x & 63)*32;
  if (t<128){ s_a[t]=ab3[t]; s_b[t]=ab3[128+t]; }
  const float* gp = gmax + ((size_t)b*NPOINT + s0)*128;
  for (int e=t; e<32*32; e+=256){
    int r = e>>5, q = e&31;
    float4 v = *(const float4*)(gp + r*128 + q*4);
    tile[r*129 + q*4+0]=v.x; tile[r*129 + q*4+1]=v.y;
    tile[r*129 + q*4+2]=v.z; tile[r*129 + q*4+3]=v.w;
  }
  __syncthreads();
  float* ob = out + 49152 + (size_t)b*128*NPOINT;
  for (int e=t; e<128*32; e+=256){
    int o = e>>5, ls = e&31;
    float v = tile[ls*129 + o];
    v = __fmaf_rn(v, s_a[o], s_b[o]);
    v = v > 0.f ? v : 0.f;
    ob[(size_t)o*NPOINT + s0 + ls] = v;
  }
}

extern "C" void kernel_launch(void* const* d_in, const int* in_sizes, int n_in,
                              void* d_out, int out_size, void* d_ws, size_t ws_size,
                              hipStream_t stream)
{
  const float* xyz    = (const float*)d_in[0];
  const float* points = (const float*)d_in[1];
  const float* W1 = (const float*)d_in[2];
  const float* b1 = (const float*)d_in[3];
  const float* g1 = (const float*)d_in[4];
  const float* be1= (const float*)d_in[5];
  const float* W2 = (const float*)d_in[6];
  const float* b2 = (const float*)d_in[7];
  const float* g2 = (const float*)d_in[8];
  const float* be2= (const float*)d_in[9];
  const float* W3 = (const float*)d_in[10];
  const float* b3 = (const float*)d_in[11];
  const float* g3 = (const float*)d_in[12];
  const float* be3= (const float*)d_in[13];
  float* out = (float*)d_out;
  char* ws = (char*)d_ws;
  // ws layout (bytes), f32 z end-to-end (~153 MB total):
  float* z     = (float*)(ws);                            // 134,217,728
  float* gmax  = (float*)(ws + 134217728);                //   8,388,608
  int*   ball  = (int*)  (ws + 142606336);                //   2,097,152
  float* part1 = (float*)(ws + 144703488);                //   2,097,152
  float* part2 = (float*)(ws + 146800640);                //   2,097,152
  float* part3 = (float*)(ws + 148897792);                //   4,194,304
  float* ab1   = (float*)(ws + 153092096);                //   512
  float* ab2   = (float*)(ws + 153092608);                //   512
  float* ab3   = (float*)(ws + 153093120);                //   1024

  hipLaunchKernelGGL(fps_kernel,   dim3(NB),   dim3(512),  0, stream, xyz, out);
  hipLaunchKernelGGL(ball_kernel,  dim3(4096), dim3(256),  0, stream, xyz, out, ball);
  hipLaunchKernelGGL(mlp1_kernel,  dim3(4096), dim3(128),  0, stream, xyz, points, out, ball, W1, b1, z, part1);
  hipLaunchKernelGGL(reduce_kernel,dim3(64),   dim3(64),   0, stream, part1, g1, be1, ab1, 64, 4096);
  hipLaunchKernelGGL(mlp2_kernel,  dim3(4096), dim3(128),  0, stream, z, ab1, W2, b2, part2);
  hipLaunchKernelGGL(reduce_kernel,dim3(64),   dim3(64),   0, stream, part2, g2, be2, ab2, 64, 4096);
  hipLaunchKernelGGL(mlp3_kernel,  dim3(4096), dim3(256),  0, stream, z, ab2, W3, b3, gmax, part3);
  hipLaunchKernelGGL(reduce_kernel,dim3(128),  dim3(64),   0, stream, part3, g3, be3, ab3, 128, 4096);
  hipLaunchKernelGGL(final_kernel, dim3(512),  dim3(256),  0, stream, gmax, ab3, out);
}